// Round 1
// baseline (1274.713 us; speedup 1.0000x reference)
//
#include <hip/hip_runtime.h>
#include <math.h>

// Problem constants
constexpr int B  = 8;
constexpr int C  = 256;   // Cin
constexpr int M  = 256;
constexpr int O  = 256;
constexpr int H  = 128;
constexpr int W  = 128;
constexpr int HW = H * W; // 16384
constexpr int K  = 128;   // top-k / kept channels

// Workspace layout (offsets in floats)
constexpr size_t WS_MEANX = 0;            // B*C   = 2048
constexpr size_t WS_MASK  = 2048;         // B*M   = 2048
constexpr size_t WS_G2    = 4096;         // B*M   = 2048
constexpr size_t WS_WT1   = 6144;         // C*M   = 65536   (pw1_w transposed: [c][o])
constexpr size_t WS_WT2   = 71680;        // 384*O = 98304   (pw_w[:, :384] transposed: [cc][o])
constexpr size_t WS_WE3   = 169984;       // B*K*9
constexpr size_t WS_WE5   = 179200;       // B*K*25
constexpr size_t WS_WE7   = 204800;       // B*K*49
constexpr size_t WS_SEL   = 262144;       // B*K*HW = 16777216 (64 MiB)
constexpr size_t WS_Y     = WS_SEL + (size_t)B * K * HW; // 16777216 more
// total = 33816576 floats = ~135 MB

// ---------------------------------------------------------------------------
// Kernel A: meanx[b][c] = mean over HW of x; also zero gap2sum accumulator.
// ---------------------------------------------------------------------------
__global__ __launch_bounds__(256) void kA(const float* __restrict__ x,
                                          float* __restrict__ ws) {
  float* meanx   = ws + WS_MEANX;
  float* gap2sum = ws + WS_G2;
  int plane = blockIdx.x;  // b*C + c  (2048 planes)
  const float* p = x + (size_t)plane * HW;
  float s = 0.f;
  for (int i = threadIdx.x; i < HW / 4; i += 256) {
    float4 v = ((const float4*)p)[i];
    s += v.x + v.y + v.z + v.w;
  }
  __shared__ float red[256];
  red[threadIdx.x] = s;
  __syncthreads();
  for (int off = 128; off > 0; off >>= 1) {
    if (threadIdx.x < off) red[threadIdx.x] += red[threadIdx.x + off];
    __syncthreads();
  }
  if (threadIdx.x == 0) meanx[plane] = red[0] * (1.f / HW);
  if (blockIdx.x < 8) gap2sum[blockIdx.x * 256 + threadIdx.x] = 0.f;
}

// ---------------------------------------------------------------------------
// Kernel T: transpose pw1_w (256x256) -> Wt1[c][o]; pw_w[:, :384] -> Wt2[cc][o]
// ---------------------------------------------------------------------------
__global__ __launch_bounds__(256) void kT(const float* __restrict__ pw1_w,
                                          const float* __restrict__ pw_w,
                                          float* __restrict__ ws) {
  float* Wt1 = ws + WS_WT1;
  float* Wt2 = ws + WS_WT2;
  int t = blockIdx.x * 256 + threadIdx.x;
  if (t < C * M) {
    int c = t / M, o = t % M;
    Wt1[t] = pw1_w[o * C + c];
  }
  if (t < 384 * O) {
    int cc = t / O, o = t % O;
    Wt2[t] = pw_w[(size_t)o * 768 + cc];  // pw_w is (256, 768); use cols <384
  }
}

// ---------------------------------------------------------------------------
// Kernel B (1 block): gap -> fc1 -> fc2 -> top-128 mask (stable tie-break).
// gap is computed exactly from meanx since pw1 is linear.
// ---------------------------------------------------------------------------
__global__ __launch_bounds__(256) void kB(const float* __restrict__ pw1_w,
                                          const float* __restrict__ pw1_b,
                                          const float* __restrict__ fc1_w,
                                          const float* __restrict__ fc1_b,
                                          const float* __restrict__ fc2_w,
                                          const float* __restrict__ fc2_b,
                                          float* __restrict__ ws) {
  const float* meanx = ws + WS_MEANX;
  float* maskg = ws + WS_MASK;
  __shared__ float s_mean[B * C];
  __shared__ float s_gap[B * M];
  __shared__ float s_hid[B * 512];
  __shared__ float s_sc[B * M];
  int t = threadIdx.x;
  for (int i = t; i < B * C; i += 256) s_mean[i] = meanx[i];
  __syncthreads();
  // gap[b][o]
  for (int i = t; i < B * M; i += 256) {
    int b = i >> 8, o = i & 255;
    const float* w  = pw1_w + (size_t)o * C;
    const float* mx = s_mean + b * C;
    float a0 = 0, a1 = 0, a2 = 0, a3 = 0;
    for (int c = 0; c < C; c += 4) {
      a0 += mx[c] * w[c];     a1 += mx[c + 1] * w[c + 1];
      a2 += mx[c + 2] * w[c + 2]; a3 += mx[c + 3] * w[c + 3];
    }
    s_gap[i] = a0 + a1 + a2 + a3 + pw1_b[o];
  }
  __syncthreads();
  // hid[b][j] = relu(gap @ fc1_w.T + b)
  for (int i = t; i < B * 512; i += 256) {
    int b = i >> 9, j = i & 511;
    const float* w = fc1_w + (size_t)j * M;
    const float* g = s_gap + b * M;
    float a0 = 0, a1 = 0, a2 = 0, a3 = 0;
    for (int c = 0; c < M; c += 4) {
      a0 += g[c] * w[c];     a1 += g[c + 1] * w[c + 1];
      a2 += g[c + 2] * w[c + 2]; a3 += g[c + 3] * w[c + 3];
    }
    float v = a0 + a1 + a2 + a3 + fc1_b[j];
    s_hid[i] = v > 0.f ? v : 0.f;
  }
  __syncthreads();
  // scores[b][o] = sigmoid(hid @ fc2_w.T + b)
  for (int i = t; i < B * M; i += 256) {
    int b = i >> 8, o = i & 255;
    const float* w = fc2_w + (size_t)o * 512;
    const float* hd = s_hid + b * 512;
    float a0 = 0, a1 = 0, a2 = 0, a3 = 0;
    for (int c = 0; c < 512; c += 4) {
      a0 += hd[c] * w[c];     a1 += hd[c + 1] * w[c + 1];
      a2 += hd[c + 2] * w[c + 2]; a3 += hd[c + 3] * w[c + 3];
    }
    float v = a0 + a1 + a2 + a3 + fc2_b[o];
    s_sc[i] = 1.f / (1.f + expf(-v));
  }
  __syncthreads();
  // mask[b][j] = 1 if rank of scores[b][j] < K (value desc, index asc)
  for (int i = t; i < B * M; i += 256) {
    int b = i >> 8, j = i & 255;
    const float* sc = s_sc + b * M;
    float sj = sc[j];
    int cnt = 0;
    for (int m = 0; m < M; m++) {
      float sm = sc[m];
      cnt += (sm > sj) || (sm == sj && m < j);
    }
    maskg[i] = (cnt < K) ? 1.f : 0.f;
  }
}

// ---------------------------------------------------------------------------
// Kernel C: h = relu(pw1(x)) as per-batch GEMM (256 x 16384, inner 256).
// Epilogue: sel[b][c][p] = relu(h)*mask for c<128; gap2sum += sum(relu(h)).
// 128x128 tile per block, 8x8 per thread.
// ---------------------------------------------------------------------------
__global__ __launch_bounds__(256) void kC(const float* __restrict__ x,
                                          const float* __restrict__ pw1_b,
                                          float* __restrict__ ws) {
  const float* Wt1   = ws + WS_WT1;
  const float* maskg = ws + WS_MASK;
  float* gap2sum     = ws + WS_G2;
  float* sel         = ws + WS_SEL;
  int b  = blockIdx.z;
  int o0 = blockIdx.y * 128;
  int p0 = blockIdx.x * 128;
  __shared__ float As[16][128];
  __shared__ float Bs[16][128];
  __shared__ float red[128][17];
  float acc[8][8] = {};
  int t = threadIdx.x, ty = t >> 4, tx = t & 15;
  const float* xb = x + (size_t)b * C * HW;
  int f1 = t, k1 = f1 >> 5, c1 = (f1 & 31) << 2;
  int f2 = t + 256, k2 = f2 >> 5, c2 = (f2 & 31) << 2;
  for (int k0 = 0; k0 < C; k0 += 16) {
    *(float4*)&As[k1][c1] = *(const float4*)&Wt1[(size_t)(k0 + k1) * M + o0 + c1];
    *(float4*)&As[k2][c2] = *(const float4*)&Wt1[(size_t)(k0 + k2) * M + o0 + c2];
    *(float4*)&Bs[k1][c1] = *(const float4*)&xb[(size_t)(k0 + k1) * HW + p0 + c1];
    *(float4*)&Bs[k2][c2] = *(const float4*)&xb[(size_t)(k0 + k2) * HW + p0 + c2];
    __syncthreads();
#pragma unroll
    for (int k = 0; k < 16; k++) {
      float a[8], bb[8];
      *(float4*)&a[0]  = *(float4*)&As[k][ty * 8];
      *(float4*)&a[4]  = *(float4*)&As[k][ty * 8 + 4];
      *(float4*)&bb[0] = *(float4*)&Bs[k][tx * 8];
      *(float4*)&bb[4] = *(float4*)&Bs[k][tx * 8 + 4];
#pragma unroll
      for (int r = 0; r < 8; r++)
#pragma unroll
        for (int c = 0; c < 8; c++) acc[r][c] += a[r] * bb[c];
    }
    __syncthreads();
  }
  // Epilogue
  float rowsum[8];
#pragma unroll
  for (int r = 0; r < 8; r++) {
    int o = o0 + ty * 8 + r;
    float bias = pw1_b[o];
    float mk = maskg[b * M + o];
    float v[8];
    float rs = 0.f;
#pragma unroll
    for (int c = 0; c < 8; c++) {
      float h = acc[r][c] + bias;
      h = h > 0.f ? h : 0.f;
      rs += h;
      v[c] = h * mk;
    }
    rowsum[r] = rs;
    if (o < K) {
      float* sp = sel + ((size_t)(b * K + o)) * HW + p0 + tx * 8;
      float4 v0; v0.x = v[0]; v0.y = v[1]; v0.z = v[2]; v0.w = v[3];
      float4 v1; v1.x = v[4]; v1.y = v[5]; v1.z = v[6]; v1.w = v[7];
      *(float4*)sp = v0;
      *(float4*)(sp + 4) = v1;
    }
  }
#pragma unroll
  for (int r = 0; r < 8; r++) red[ty * 8 + r][tx] = rowsum[r];
  __syncthreads();
  if (t < 128) {
    float s = 0.f;
#pragma unroll
    for (int i = 0; i < 16; i++) s += red[t][i];
    atomicAdd(&gap2sum[b * M + o0 + t], s);
  }
}

// ---------------------------------------------------------------------------
// Kernel D (1 block): offsets = tanh(gap2 @ off_w.T + off_b); build effective
// depthwise weights w = dw*(1+sigmoid(off[2i])) + tanh(off[2i+1]).
// ---------------------------------------------------------------------------
__global__ __launch_bounds__(256) void kD(const float* __restrict__ off_w,
                                          const float* __restrict__ off_b,
                                          const float* __restrict__ dw3,
                                          const float* __restrict__ dw5,
                                          const float* __restrict__ dw7,
                                          float* __restrict__ ws) {
  const float* gap2sum = ws + WS_G2;
  float* wE3 = ws + WS_WE3;
  float* wE5 = ws + WS_WE5;
  float* wE7 = ws + WS_WE7;
  __shared__ float s_off[48];
  int t = threadIdx.x;
  if (t < 48) {
    int b = t / 6, j = t % 6;
    const float* g = gap2sum + b * M;
    const float* w = off_w + j * M;
    float a = 0.f;
    for (int c = 0; c < M; c++) a += (g[c] * (1.f / HW)) * w[c];
    s_off[t] = tanhf(a + off_b[j]);
  }
  __syncthreads();
  for (int i = t; i < B * K * 9; i += 256) {
    int b = i / (K * 9), rem = i % (K * 9), c = rem / 9, tap = rem % 9;
    float sc = 1.f + 1.f / (1.f + expf(-s_off[b * 6 + 0]));
    float sh = tanhf(s_off[b * 6 + 1]);
    wE3[i] = dw3[c * 9 + tap] * sc + sh;
  }
  for (int i = t; i < B * K * 25; i += 256) {
    int b = i / (K * 25), rem = i % (K * 25), c = rem / 25, tap = rem % 25;
    float sc = 1.f + 1.f / (1.f + expf(-s_off[b * 6 + 2]));
    float sh = tanhf(s_off[b * 6 + 3]);
    wE5[i] = dw5[c * 25 + tap] * sc + sh;
  }
  for (int i = t; i < B * K * 49; i += 256) {
    int b = i / (K * 49), rem = i % (K * 49), c = rem / 49, tap = rem % 49;
    float sc = 1.f + 1.f / (1.f + expf(-s_off[b * 6 + 4]));
    float sh = tanhf(s_off[b * 6 + 5]);
    wE7[i] = dw7[c * 49 + tap] * sc + sh;
  }
}

// ---------------------------------------------------------------------------
// Kernel E<KS>: depthwise conv of one 128x128 plane chunk (32 rows) with the
// per-(b,c) effective weights. Zero padding handled at LDS-fill time.
// ---------------------------------------------------------------------------
template <int KS>
__global__ __launch_bounds__(256) void kE(const float* __restrict__ sel,
                                          const float* __restrict__ wE,
                                          float* __restrict__ y) {
  constexpr int P  = (KS - 1) / 2;
  constexpr int SH = 32 + 2 * P;
  constexpr int SW = 128 + 2 * P;
  __shared__ float sm[SH][SW];
  int blk = blockIdx.x;
  int chunk = blk & 3;
  int plane = blk >> 2;  // b*K + c
  int r0 = chunk * 32;
  const float* in = sel + (size_t)plane * HW;
  for (int i = threadIdx.x; i < SH * SW; i += 256) {
    int rr = i / SW, cc = i % SW;
    int gy = r0 - P + rr, gx = cc - P;
    float v = 0.f;
    if (gy >= 0 && gy < H && gx >= 0 && gx < W) v = in[gy * W + gx];
    sm[rr][cc] = v;
  }
  __syncthreads();
  float w[KS * KS];
  const float* wp = wE + (size_t)plane * (KS * KS);
#pragma unroll
  for (int i = 0; i < KS * KS; i++) w[i] = wp[i];
  int col   = threadIdx.x & 127;
  int rhalf = threadIdx.x >> 7;  // 0 or 1: rows rhalf*16 .. rhalf*16+15
  float acc[16];
#pragma unroll
  for (int r = 0; r < 16; r++) acc[r] = 0.f;
#pragma unroll
  for (int iy = 0; iy < 16 + 2 * P; iy++) {
    float v[KS];
#pragma unroll
    for (int dx = 0; dx < KS; dx++) v[dx] = sm[rhalf * 16 + iy][col + dx];
#pragma unroll
    for (int rr = 0; rr < 16; rr++) {
      int dy = iy - rr;
      if (dy >= 0 && dy < KS) {
#pragma unroll
        for (int dx = 0; dx < KS; dx++) acc[rr] += v[dx] * w[dy * KS + dx];
      }
    }
  }
  float* outp = y + (size_t)plane * HW;
#pragma unroll
  for (int rr = 0; rr < 16; rr++) {
    int orow = rhalf * 16 + rr;
    outp[(size_t)(r0 + orow) * W + col] = acc[rr];
  }
}

// ---------------------------------------------------------------------------
// Kernel F: out[b][o][p] (+)= sum_c Wt2[branch*128+c][o] * y[b][c][p]
// branch 0 also adds pw_b + residual x and initializes out.
// ---------------------------------------------------------------------------
__global__ __launch_bounds__(256) void kF(const float* __restrict__ x,
                                          const float* __restrict__ pw_b,
                                          const float* __restrict__ ws,
                                          float* __restrict__ out, int branch) {
  const float* Wt2 = ws + WS_WT2;
  const float* y   = ws + WS_Y;
  int b  = blockIdx.z;
  int o0 = blockIdx.y * 128;
  int p0 = blockIdx.x * 128;
  __shared__ float As[16][128];
  __shared__ float Bs[16][128];
  float acc[8][8] = {};
  int t = threadIdx.x, ty = t >> 4, tx = t & 15;
  const float* yb = y + (size_t)b * K * HW;
  const float* wbase = Wt2 + (size_t)branch * K * M;
  int f1 = t, k1 = f1 >> 5, c1 = (f1 & 31) << 2;
  int f2 = t + 256, k2 = f2 >> 5, c2 = (f2 & 31) << 2;
  for (int k0 = 0; k0 < K; k0 += 16) {
    *(float4*)&As[k1][c1] = *(const float4*)&wbase[(size_t)(k0 + k1) * M + o0 + c1];
    *(float4*)&As[k2][c2] = *(const float4*)&wbase[(size_t)(k0 + k2) * M + o0 + c2];
    *(float4*)&Bs[k1][c1] = *(const float4*)&yb[(size_t)(k0 + k1) * HW + p0 + c1];
    *(float4*)&Bs[k2][c2] = *(const float4*)&yb[(size_t)(k0 + k2) * HW + p0 + c2];
    __syncthreads();
#pragma unroll
    for (int k = 0; k < 16; k++) {
      float a[8], bb[8];
      *(float4*)&a[0]  = *(float4*)&As[k][ty * 8];
      *(float4*)&a[4]  = *(float4*)&As[k][ty * 8 + 4];
      *(float4*)&bb[0] = *(float4*)&Bs[k][tx * 8];
      *(float4*)&bb[4] = *(float4*)&Bs[k][tx * 8 + 4];
#pragma unroll
      for (int r = 0; r < 8; r++)
#pragma unroll
        for (int c = 0; c < 8; c++) acc[r][c] += a[r] * bb[c];
    }
    __syncthreads();
  }
  // Epilogue
#pragma unroll
  for (int r = 0; r < 8; r++) {
    int o = o0 + ty * 8 + r;
    size_t rowoff = ((size_t)b * O + o) * HW + p0 + tx * 8;
    float v[8];
#pragma unroll
    for (int c = 0; c < 8; c++) v[c] = acc[r][c];
    if (branch == 0) {
      float bias = pw_b[o];
      float4 x0 = *(const float4*)&x[rowoff];
      float4 x1 = *(const float4*)&x[rowoff + 4];
      v[0] += bias + x0.x; v[1] += bias + x0.y; v[2] += bias + x0.z; v[3] += bias + x0.w;
      v[4] += bias + x1.x; v[5] += bias + x1.y; v[6] += bias + x1.z; v[7] += bias + x1.w;
    } else {
      float4 p0v = *(const float4*)&out[rowoff];
      float4 p1v = *(const float4*)&out[rowoff + 4];
      v[0] += p0v.x; v[1] += p0v.y; v[2] += p0v.z; v[3] += p0v.w;
      v[4] += p1v.x; v[5] += p1v.y; v[6] += p1v.z; v[7] += p1v.w;
    }
    float4 s0; s0.x = v[0]; s0.y = v[1]; s0.z = v[2]; s0.w = v[3];
    float4 s1; s1.x = v[4]; s1.y = v[5]; s1.z = v[6]; s1.w = v[7];
    *(float4*)&out[rowoff] = s0;
    *(float4*)&out[rowoff + 4] = s1;
  }
}

// ---------------------------------------------------------------------------
extern "C" void kernel_launch(void* const* d_in, const int* in_sizes, int n_in,
                              void* d_out, int out_size, void* d_ws, size_t ws_size,
                              hipStream_t stream) {
  const float* x     = (const float*)d_in[0];
  const float* pw1_w = (const float*)d_in[1];
  const float* pw1_b = (const float*)d_in[2];
  const float* fc1_w = (const float*)d_in[3];
  const float* fc1_b = (const float*)d_in[4];
  const float* fc2_w = (const float*)d_in[5];
  const float* fc2_b = (const float*)d_in[6];
  const float* off_w = (const float*)d_in[7];
  const float* off_b = (const float*)d_in[8];
  const float* dw3   = (const float*)d_in[9];
  const float* dw5   = (const float*)d_in[10];
  const float* dw7   = (const float*)d_in[11];
  const float* pw_w  = (const float*)d_in[12];
  const float* pw_b  = (const float*)d_in[13];
  float* out = (float*)d_out;
  float* ws  = (float*)d_ws;

  kA<<<B * C, 256, 0, stream>>>(x, ws);
  kT<<<384, 256, 0, stream>>>(pw1_w, pw_w, ws);
  kB<<<1, 256, 0, stream>>>(pw1_w, pw1_b, fc1_w, fc1_b, fc2_w, fc2_b, ws);
  dim3 gC(HW / 128, M / 128, B);
  kC<<<gC, 256, 0, stream>>>(x, pw1_b, ws);
  kD<<<1, 256, 0, stream>>>(off_w, off_b, dw3, dw5, dw7, ws);

  float* selbuf = ws + WS_SEL;
  float* ybuf   = ws + WS_Y;
  dim3 gF(HW / 128, O / 128, B);

  kE<3><<<B * K * 4, 256, 0, stream>>>(selbuf, ws + WS_WE3, ybuf);
  kF<<<gF, 256, 0, stream>>>(x, pw_b, ws, out, 0);
  kE<5><<<B * K * 4, 256, 0, stream>>>(selbuf, ws + WS_WE5, ybuf);
  kF<<<gF, 256, 0, stream>>>(x, pw_b, ws, out, 1);
  kE<7><<<B * K * 4, 256, 0, stream>>>(selbuf, ws + WS_WE7, ybuf);
  kF<<<gF, 256, 0, stream>>>(x, pw_b, ws, out, 2);
}

// Round 2
// 960.795 us; speedup vs baseline: 1.3267x; 1.3267x over previous
//
#include <hip/hip_runtime.h>
#include <math.h>

// Problem constants
constexpr int B  = 8;
constexpr int C  = 256;   // Cin
constexpr int M  = 256;
constexpr int O  = 256;
constexpr int H  = 128;
constexpr int W  = 128;
constexpr int HW = H * W; // 16384
constexpr int K  = 128;   // top-k / kept channels

// Workspace layout (offsets in floats)
constexpr size_t WS_MEANX = 0;            // B*C   = 2048
constexpr size_t WS_MASK  = 2048;         // B*M   = 2048
constexpr size_t WS_G2    = 4096;         // B*M   = 2048
constexpr size_t WS_WT1   = 6144;         // C*M   = 65536   (pw1_w transposed: [c][o])
constexpr size_t WS_WT2   = 71680;        // 384*O = 98304   (pw_w[:, :384] transposed: [cc][o])
constexpr size_t WS_WE3   = 169984;       // B*K*9  = 9216
constexpr size_t WS_WE5   = 179200;       // B*K*25 = 25600
constexpr size_t WS_WE7   = 204800;       // B*K*49 = 50176
constexpr size_t WS_OFF   = 254976;       // 48 (24 scale + 24 shift)
constexpr size_t WS_SEL   = 262144;       // B*K*HW = 16777216 (64 MiB)
constexpr size_t WS_Y     = WS_SEL + (size_t)B * K * HW; // 16777216 more
// total = 33816576 floats = ~135 MB

// ---------------------------------------------------------------------------
// Kernel A: meanx[b][c] = mean over HW of x; also zero gap2sum accumulator.
// ---------------------------------------------------------------------------
__global__ __launch_bounds__(256) void kA(const float* __restrict__ x,
                                          float* __restrict__ ws) {
  float* meanx   = ws + WS_MEANX;
  float* gap2sum = ws + WS_G2;
  int plane = blockIdx.x;  // b*C + c  (2048 planes)
  const float* p = x + (size_t)plane * HW;
  float s = 0.f;
  for (int i = threadIdx.x; i < HW / 4; i += 256) {
    float4 v = ((const float4*)p)[i];
    s += v.x + v.y + v.z + v.w;
  }
  __shared__ float red[256];
  red[threadIdx.x] = s;
  __syncthreads();
  for (int off = 128; off > 0; off >>= 1) {
    if (threadIdx.x < off) red[threadIdx.x] += red[threadIdx.x + off];
    __syncthreads();
  }
  if (threadIdx.x == 0) meanx[plane] = red[0] * (1.f / HW);
  if (blockIdx.x < 8) gap2sum[blockIdx.x * 256 + threadIdx.x] = 0.f;
}

// ---------------------------------------------------------------------------
// Kernel T: transpose pw1_w (256x256) -> Wt1[c][o]; pw_w[:, :384] -> Wt2[cc][o]
// ---------------------------------------------------------------------------
__global__ __launch_bounds__(256) void kT(const float* __restrict__ pw1_w,
                                          const float* __restrict__ pw_w,
                                          float* __restrict__ ws) {
  float* Wt1 = ws + WS_WT1;
  float* Wt2 = ws + WS_WT2;
  int t = blockIdx.x * 256 + threadIdx.x;
  if (t < C * M) {
    int c = t / M, o = t % M;
    Wt1[t] = pw1_w[o * C + c];
  }
  if (t < 384 * O) {
    int cc = t / O, o = t % O;
    Wt2[t] = pw_w[(size_t)o * 768 + cc];  // pw_w is (256, 768); use cols <384
  }
}

// ---------------------------------------------------------------------------
// Kernel B: 8 blocks (one per batch). Wave-per-output coalesced dots with
// butterfly reduce; 4 outputs in flight per wave for latency overlap.
// gap -> fc1(relu) -> fc2(sigmoid) -> top-128 mask (stable tie-break).
// ---------------------------------------------------------------------------
__global__ __launch_bounds__(256) void kB(const float* __restrict__ pw1_w,
                                          const float* __restrict__ pw1_b,
                                          const float* __restrict__ fc1_w,
                                          const float* __restrict__ fc1_b,
                                          const float* __restrict__ fc2_w,
                                          const float* __restrict__ fc2_b,
                                          float* __restrict__ ws) {
  int b = blockIdx.x;
  const float* meanx = ws + WS_MEANX + b * C;
  const float* g2    = ws + WS_G2;  // unused here
  (void)g2;
  float* maskg = ws + WS_MASK;
  __shared__ float s_gap[M];
  __shared__ float s_hid[512];
  __shared__ float s_sc[M];
  int t = threadIdx.x;
  int lane = t & 63, wv = t >> 6;  // 4 waves

  // Phase 1: gap[o] = dot(meanx, pw1_w[o]) + pw1_b[o]
  float4 mx = ((const float4*)meanx)[lane];
  for (int o0 = wv * 64; o0 < wv * 64 + 64; o0 += 4) {
    float s[4];
#pragma unroll
    for (int j = 0; j < 4; j++) {
      float4 w = ((const float4*)(pw1_w + (size_t)(o0 + j) * C))[lane];
      s[j] = mx.x * w.x + mx.y * w.y + mx.z * w.z + mx.w * w.w;
    }
#pragma unroll
    for (int off = 32; off > 0; off >>= 1)
#pragma unroll
      for (int j = 0; j < 4; j++) s[j] += __shfl_xor(s[j], off, 64);
    if (lane == 0) {
      s_gap[o0 + 0] = s[0] + pw1_b[o0 + 0];
      s_gap[o0 + 1] = s[1] + pw1_b[o0 + 1];
      s_gap[o0 + 2] = s[2] + pw1_b[o0 + 2];
      s_gap[o0 + 3] = s[3] + pw1_b[o0 + 3];
    }
  }
  __syncthreads();

  // Phase 2: hid[j] = relu(dot(gap, fc1_w[j]) + fc1_b[j]), j in [0,512)
  float4 g4 = ((const float4*)s_gap)[lane];
  for (int j0 = wv * 128; j0 < wv * 128 + 128; j0 += 4) {
    float s[4];
#pragma unroll
    for (int j = 0; j < 4; j++) {
      float4 w = ((const float4*)(fc1_w + (size_t)(j0 + j) * M))[lane];
      s[j] = g4.x * w.x + g4.y * w.y + g4.z * w.z + g4.w * w.w;
    }
#pragma unroll
    for (int off = 32; off > 0; off >>= 1)
#pragma unroll
      for (int j = 0; j < 4; j++) s[j] += __shfl_xor(s[j], off, 64);
    if (lane == 0) {
#pragma unroll
      for (int j = 0; j < 4; j++) {
        float v = s[j] + fc1_b[j0 + j];
        s_hid[j0 + j] = v > 0.f ? v : 0.f;
      }
    }
  }
  __syncthreads();

  // Phase 3: scores[o] = sigmoid(dot(hid, fc2_w[o]) + fc2_b[o]), len 512
  float4 h0 = ((const float4*)s_hid)[lane];
  float4 h1 = ((const float4*)s_hid)[lane + 64];
  for (int o0 = wv * 64; o0 < wv * 64 + 64; o0 += 4) {
    float s[4];
#pragma unroll
    for (int j = 0; j < 4; j++) {
      const float4* wr = (const float4*)(fc2_w + (size_t)(o0 + j) * 512);
      float4 w0 = wr[lane];
      float4 w1 = wr[lane + 64];
      s[j] = h0.x * w0.x + h0.y * w0.y + h0.z * w0.z + h0.w * w0.w +
             h1.x * w1.x + h1.y * w1.y + h1.z * w1.z + h1.w * w1.w;
    }
#pragma unroll
    for (int off = 32; off > 0; off >>= 1)
#pragma unroll
      for (int j = 0; j < 4; j++) s[j] += __shfl_xor(s[j], off, 64);
    if (lane == 0) {
#pragma unroll
      for (int j = 0; j < 4; j++) {
        float v = s[j] + fc2_b[o0 + j];
        s_sc[o0 + j] = 1.f / (1.f + expf(-v));
      }
    }
  }
  __syncthreads();

  // Phase 4: mask[j] = 1 if rank(scores[j]) < K (value desc, index asc)
  {
    int j = t;
    float sj = s_sc[j];
    int cnt = 0;
    for (int m = 0; m < M; m++) {
      float sm = s_sc[m];
      cnt += (sm > sj) || (sm == sj && m < j);
    }
    maskg[b * M + j] = (cnt < K) ? 1.f : 0.f;
  }
}

// ---------------------------------------------------------------------------
// Kernel C: h = relu(pw1(x)) as per-batch GEMM (256 x 16384, inner 256).
// Epilogue: sel[b][c][p] = relu(h)*mask for c<128; gap2sum += sum(relu(h)).
// 128x128 tile per block, 8x8 per thread.
// ---------------------------------------------------------------------------
__global__ __launch_bounds__(256) void kC(const float* __restrict__ x,
                                          const float* __restrict__ pw1_b,
                                          float* __restrict__ ws) {
  const float* Wt1   = ws + WS_WT1;
  const float* maskg = ws + WS_MASK;
  float* gap2sum     = ws + WS_G2;
  float* sel         = ws + WS_SEL;
  int b  = blockIdx.z;
  int o0 = blockIdx.y * 128;
  int p0 = blockIdx.x * 128;
  __shared__ float As[16][128];
  __shared__ float Bs[16][128];
  __shared__ float red[128][17];
  float acc[8][8] = {};
  int t = threadIdx.x, ty = t >> 4, tx = t & 15;
  const float* xb = x + (size_t)b * C * HW;
  int f1 = t, k1 = f1 >> 5, c1 = (f1 & 31) << 2;
  int f2 = t + 256, k2 = f2 >> 5, c2 = (f2 & 31) << 2;
  for (int k0 = 0; k0 < C; k0 += 16) {
    *(float4*)&As[k1][c1] = *(const float4*)&Wt1[(size_t)(k0 + k1) * M + o0 + c1];
    *(float4*)&As[k2][c2] = *(const float4*)&Wt1[(size_t)(k0 + k2) * M + o0 + c2];
    *(float4*)&Bs[k1][c1] = *(const float4*)&xb[(size_t)(k0 + k1) * HW + p0 + c1];
    *(float4*)&Bs[k2][c2] = *(const float4*)&xb[(size_t)(k0 + k2) * HW + p0 + c2];
    __syncthreads();
#pragma unroll
    for (int k = 0; k < 16; k++) {
      float a[8], bb[8];
      *(float4*)&a[0]  = *(float4*)&As[k][ty * 8];
      *(float4*)&a[4]  = *(float4*)&As[k][ty * 8 + 4];
      *(float4*)&bb[0] = *(float4*)&Bs[k][tx * 8];
      *(float4*)&bb[4] = *(float4*)&Bs[k][tx * 8 + 4];
#pragma unroll
      for (int r = 0; r < 8; r++)
#pragma unroll
        for (int c = 0; c < 8; c++) acc[r][c] += a[r] * bb[c];
    }
    __syncthreads();
  }
  // Epilogue
  float rowsum[8];
#pragma unroll
  for (int r = 0; r < 8; r++) {
    int o = o0 + ty * 8 + r;
    float bias = pw1_b[o];
    float mk = maskg[b * M + o];
    float v[8];
    float rs = 0.f;
#pragma unroll
    for (int c = 0; c < 8; c++) {
      float h = acc[r][c] + bias;
      h = h > 0.f ? h : 0.f;
      rs += h;
      v[c] = h * mk;
    }
    rowsum[r] = rs;
    if (o < K) {
      float* sp = sel + ((size_t)(b * K + o)) * HW + p0 + tx * 8;
      float4 v0; v0.x = v[0]; v0.y = v[1]; v0.z = v[2]; v0.w = v[3];
      float4 v1; v1.x = v[4]; v1.y = v[5]; v1.z = v[6]; v1.w = v[7];
      *(float4*)sp = v0;
      *(float4*)(sp + 4) = v1;
    }
  }
#pragma unroll
  for (int r = 0; r < 8; r++) red[ty * 8 + r][tx] = rowsum[r];
  __syncthreads();
  if (t < 128) {
    float s = 0.f;
#pragma unroll
    for (int i = 0; i < 16; i++) s += red[t][i];
    atomicAdd(&gap2sum[b * M + o0 + t], s);
  }
}

// ---------------------------------------------------------------------------
// Kernel D1 (1 block): offsets = tanh(gap2 @ off_w.T + off_b);
// emit per-(b,branch) scale = 1+sigmoid(off[2i]) and shift = tanh(off[2i+1]).
// Wave-per-dot, coalesced, butterfly reduce. 48 dots total.
// ---------------------------------------------------------------------------
__global__ __launch_bounds__(256) void kD1(const float* __restrict__ off_w,
                                           const float* __restrict__ off_b,
                                           float* __restrict__ ws) {
  const float* gap2sum = ws + WS_G2;
  float* offv = ws + WS_OFF;  // [0..23]=scale(b*3+i), [24..47]=shift
  __shared__ float s_off[48];
  int t = threadIdx.x;
  int lane = t & 63, wv = t >> 6;
  // 48 dots: id = b*6 + j
  for (int id = wv; id < 48; id += 4) {
    int b = id / 6, j = id % 6;
    float4 g = ((const float4*)(gap2sum + b * M))[lane];
    float4 w = ((const float4*)(off_w + (size_t)j * M))[lane];
    float s = (g.x * w.x + g.y * w.y + g.z * w.z + g.w * w.w) * (1.f / HW);
#pragma unroll
    for (int off = 32; off > 0; off >>= 1) s += __shfl_xor(s, off, 64);
    if (lane == 0) s_off[id] = tanhf(s + off_b[j]);
  }
  __syncthreads();
  if (t < 24) {
    int b = t / 3, i = t % 3;
    offv[t]      = 1.f + 1.f / (1.f + expf(-s_off[b * 6 + 2 * i]));
    offv[24 + t] = tanhf(s_off[b * 6 + 2 * i + 1]);
  }
}

// ---------------------------------------------------------------------------
// Kernel D2: expand effective depthwise weights (pure FMA, gridded).
// ---------------------------------------------------------------------------
__global__ __launch_bounds__(256) void kD2(const float* __restrict__ dw3,
                                           const float* __restrict__ dw5,
                                           const float* __restrict__ dw7,
                                           float* __restrict__ ws) {
  const float* offv = ws + WS_OFF;
  float* wE3 = ws + WS_WE3;
  float* wE5 = ws + WS_WE5;
  float* wE7 = ws + WS_WE7;
  int tid = blockIdx.x * 256 + threadIdx.x;
  int stride = gridDim.x * 256;
  for (int i = tid; i < B * K * 9; i += stride) {
    int b = i / (K * 9), rem = i % (K * 9);
    wE3[i] = dw3[rem] * offv[b * 3 + 0] + offv[24 + b * 3 + 0];
  }
  for (int i = tid; i < B * K * 25; i += stride) {
    int b = i / (K * 25), rem = i % (K * 25);
    wE5[i] = dw5[rem] * offv[b * 3 + 1] + offv[24 + b * 3 + 1];
  }
  for (int i = tid; i < B * K * 49; i += stride) {
    int b = i / (K * 49), rem = i % (K * 49);
    wE7[i] = dw7[rem] * offv[b * 3 + 2] + offv[24 + b * 3 + 2];
  }
}

// ---------------------------------------------------------------------------
// Kernel E<KS>: depthwise conv of one 128x128 plane chunk (32 rows) with the
// per-(b,c) effective weights. Zero padding handled at LDS-fill time.
// ---------------------------------------------------------------------------
template <int KS>
__global__ __launch_bounds__(256) void kE(const float* __restrict__ sel,
                                          const float* __restrict__ wE,
                                          float* __restrict__ y) {
  constexpr int P  = (KS - 1) / 2;
  constexpr int SH = 32 + 2 * P;
  constexpr int SW = 128 + 2 * P;
  __shared__ float sm[SH][SW];
  int blk = blockIdx.x;
  int chunk = blk & 3;
  int plane = blk >> 2;  // b*K + c
  int r0 = chunk * 32;
  const float* in = sel + (size_t)plane * HW;
  for (int i = threadIdx.x; i < SH * SW; i += 256) {
    int rr = i / SW, cc = i % SW;
    int gy = r0 - P + rr, gx = cc - P;
    float v = 0.f;
    if (gy >= 0 && gy < H && gx >= 0 && gx < W) v = in[gy * W + gx];
    sm[rr][cc] = v;
  }
  __syncthreads();
  float w[KS * KS];
  const float* wp = wE + (size_t)plane * (KS * KS);
#pragma unroll
  for (int i = 0; i < KS * KS; i++) w[i] = wp[i];
  int col   = threadIdx.x & 127;
  int rhalf = threadIdx.x >> 7;  // 0 or 1: rows rhalf*16 .. rhalf*16+15
  float acc[16];
#pragma unroll
  for (int r = 0; r < 16; r++) acc[r] = 0.f;
#pragma unroll
  for (int iy = 0; iy < 16 + 2 * P; iy++) {
    float v[KS];
#pragma unroll
    for (int dx = 0; dx < KS; dx++) v[dx] = sm[rhalf * 16 + iy][col + dx];
#pragma unroll
    for (int rr = 0; rr < 16; rr++) {
      int dy = iy - rr;
      if (dy >= 0 && dy < KS) {
#pragma unroll
        for (int dx = 0; dx < KS; dx++) acc[rr] += v[dx] * w[dy * KS + dx];
      }
    }
  }
  float* outp = y + (size_t)plane * HW;
#pragma unroll
  for (int rr = 0; rr < 16; rr++) {
    int orow = rhalf * 16 + rr;
    outp[(size_t)(r0 + orow) * W + col] = acc[rr];
  }
}

// ---------------------------------------------------------------------------
// Kernel F: out[b][o][p] (+)= sum_c Wt2[branch*128+c][o] * y[b][c][p]
// branch 0 also adds pw_b + residual x and initializes out.
// ---------------------------------------------------------------------------
__global__ __launch_bounds__(256) void kF(const float* __restrict__ x,
                                          const float* __restrict__ pw_b,
                                          const float* __restrict__ ws,
                                          float* __restrict__ out, int branch) {
  const float* Wt2 = ws + WS_WT2;
  const float* y   = ws + WS_Y;
  int b  = blockIdx.z;
  int o0 = blockIdx.y * 128;
  int p0 = blockIdx.x * 128;
  __shared__ float As[16][128];
  __shared__ float Bs[16][128];
  float acc[8][8] = {};
  int t = threadIdx.x, ty = t >> 4, tx = t & 15;
  const float* yb = y + (size_t)b * K * HW;
  const float* wbase = Wt2 + (size_t)branch * K * M;
  int f1 = t, k1 = f1 >> 5, c1 = (f1 & 31) << 2;
  int f2 = t + 256, k2 = f2 >> 5, c2 = (f2 & 31) << 2;
  for (int k0 = 0; k0 < K; k0 += 16) {
    *(float4*)&As[k1][c1] = *(const float4*)&wbase[(size_t)(k0 + k1) * M + o0 + c1];
    *(float4*)&As[k2][c2] = *(const float4*)&wbase[(size_t)(k0 + k2) * M + o0 + c2];
    *(float4*)&Bs[k1][c1] = *(const float4*)&yb[(size_t)(k0 + k1) * HW + p0 + c1];
    *(float4*)&Bs[k2][c2] = *(const float4*)&yb[(size_t)(k0 + k2) * HW + p0 + c2];
    __syncthreads();
#pragma unroll
    for (int k = 0; k < 16; k++) {
      float a[8], bb[8];
      *(float4*)&a[0]  = *(float4*)&As[k][ty * 8];
      *(float4*)&a[4]  = *(float4*)&As[k][ty * 8 + 4];
      *(float4*)&bb[0] = *(float4*)&Bs[k][tx * 8];
      *(float4*)&bb[4] = *(float4*)&Bs[k][tx * 8 + 4];
#pragma unroll
      for (int r = 0; r < 8; r++)
#pragma unroll
        for (int c = 0; c < 8; c++) acc[r][c] += a[r] * bb[c];
    }
    __syncthreads();
  }
  // Epilogue
#pragma unroll
  for (int r = 0; r < 8; r++) {
    int o = o0 + ty * 8 + r;
    size_t rowoff = ((size_t)b * O + o) * HW + p0 + tx * 8;
    float v[8];
#pragma unroll
    for (int c = 0; c < 8; c++) v[c] = acc[r][c];
    if (branch == 0) {
      float bias = pw_b[o];
      float4 x0 = *(const float4*)&x[rowoff];
      float4 x1 = *(const float4*)&x[rowoff + 4];
      v[0] += bias + x0.x; v[1] += bias + x0.y; v[2] += bias + x0.z; v[3] += bias + x0.w;
      v[4] += bias + x1.x; v[5] += bias + x1.y; v[6] += bias + x1.z; v[7] += bias + x1.w;
    } else {
      float4 p0v = *(const float4*)&out[rowoff];
      float4 p1v = *(const float4*)&out[rowoff + 4];
      v[0] += p0v.x; v[1] += p0v.y; v[2] += p0v.z; v[3] += p0v.w;
      v[4] += p1v.x; v[5] += p1v.y; v[6] += p1v.z; v[7] += p1v.w;
    }
    float4 s0; s0.x = v[0]; s0.y = v[1]; s0.z = v[2]; s0.w = v[3];
    float4 s1; s1.x = v[4]; s1.y = v[5]; s1.z = v[6]; s1.w = v[7];
    *(float4*)&out[rowoff] = s0;
    *(float4*)&out[rowoff + 4] = s1;
  }
}

// ---------------------------------------------------------------------------
extern "C" void kernel_launch(void* const* d_in, const int* in_sizes, int n_in,
                              void* d_out, int out_size, void* d_ws, size_t ws_size,
                              hipStream_t stream) {
  const float* x     = (const float*)d_in[0];
  const float* pw1_w = (const float*)d_in[1];
  const float* pw1_b = (const float*)d_in[2];
  const float* fc1_w = (const float*)d_in[3];
  const float* fc1_b = (const float*)d_in[4];
  const float* fc2_w = (const float*)d_in[5];
  const float* fc2_b = (const float*)d_in[6];
  const float* off_w = (const float*)d_in[7];
  const float* off_b = (const float*)d_in[8];
  const float* dw3   = (const float*)d_in[9];
  const float* dw5   = (const float*)d_in[10];
  const float* dw7   = (const float*)d_in[11];
  const float* pw_w  = (const float*)d_in[12];
  const float* pw_b  = (const float*)d_in[13];
  float* out = (float*)d_out;
  float* ws  = (float*)d_ws;

  kA<<<B * C, 256, 0, stream>>>(x, ws);
  kT<<<384, 256, 0, stream>>>(pw1_w, pw_w, ws);
  kB<<<B, 256, 0, stream>>>(pw1_w, pw1_b, fc1_w, fc1_b, fc2_w, fc2_b, ws);
  dim3 gC(HW / 128, M / 128, B);
  kC<<<gC, 256, 0, stream>>>(x, pw1_b, ws);
  kD1<<<1, 256, 0, stream>>>(off_w, off_b, ws);
  kD2<<<84, 256, 0, stream>>>(dw3, dw5, dw7, ws);

  float* selbuf = ws + WS_SEL;
  float* ybuf   = ws + WS_Y;
  dim3 gF(HW / 128, O / 128, B);

  kE<3><<<B * K * 4, 256, 0, stream>>>(selbuf, ws + WS_WE3, ybuf);
  kF<<<gF, 256, 0, stream>>>(x, pw_b, ws, out, 0);
  kE<5><<<B * K * 4, 256, 0, stream>>>(selbuf, ws + WS_WE5, ybuf);
  kF<<<gF, 256, 0, stream>>>(x, pw_b, ws, out, 1);
  kE<7><<<B * K * 4, 256, 0, stream>>>(selbuf, ws + WS_WE7, ybuf);
  kF<<<gF, 256, 0, stream>>>(x, pw_b, ws, out, 2);
}

// Round 3
// 645.274 us; speedup vs baseline: 1.9755x; 1.4890x over previous
//
#include <hip/hip_runtime.h>
#include <math.h>

// Problem constants
constexpr int B  = 8;
constexpr int C  = 256;   // Cin
constexpr int M  = 256;
constexpr int O  = 256;
constexpr int H  = 128;
constexpr int W  = 128;
constexpr int HW = H * W; // 16384
constexpr int K  = 128;   // top-k / kept channels

using f16  = _Float16;
using f16x8 = __attribute__((ext_vector_type(8))) _Float16;
using f32x4 = __attribute__((ext_vector_type(4))) float;

// Workspace layout (offsets in float units)
constexpr size_t WS_MEANX = 0;        // 2048
constexpr size_t WS_MASK  = 2048;     // 2048
constexpr size_t WS_G2    = 4096;     // 2048
constexpr size_t WS_OFF   = 6144;     // 48 (pad to 64)
constexpr size_t WS_WE3   = 6208;     // 9216
constexpr size_t WS_WE5   = 15424;    // 25600
constexpr size_t WS_WE7   = 41024;    // 50176
constexpr size_t WS_WT1F  = 91200;    // 65536 f16 -> 32768 slots  (pw1_w as f16, [o][c])
constexpr size_t WS_WT2F  = 123968;   // 98304 f16 -> 49152 slots  (pw_w[:, :384] as f16, [o][cc])
constexpr size_t WS_SELH  = 173120;   // B*K*HW f16 -> 8388608 slots (33.5 MB)
constexpr size_t WS_YH    = 8561728;  // 3*B*K*HW f16 -> 25165824 slots (100.6 MB)
// end = 33727552 floats = 134.91 MB (<= previous proven 135.27 MB footprint)

// ---------------------------------------------------------------------------
// Kernel A: meanx[b][c] = mean over HW of x; also zero gap2sum accumulator.
// ---------------------------------------------------------------------------
__global__ __launch_bounds__(256) void kA(const float* __restrict__ x,
                                          float* __restrict__ ws) {
  float* meanx   = ws + WS_MEANX;
  float* gap2sum = ws + WS_G2;
  int plane = blockIdx.x;  // b*C + c
  const float* p = x + (size_t)plane * HW;
  float s = 0.f;
  for (int i = threadIdx.x; i < HW / 4; i += 256) {
    float4 v = ((const float4*)p)[i];
    s += v.x + v.y + v.z + v.w;
  }
  __shared__ float red[256];
  red[threadIdx.x] = s;
  __syncthreads();
  for (int off = 128; off > 0; off >>= 1) {
    if (threadIdx.x < off) red[threadIdx.x] += red[threadIdx.x + off];
    __syncthreads();
  }
  if (threadIdx.x == 0) meanx[plane] = red[0] * (1.f / HW);
  if (blockIdx.x < 8) gap2sum[blockIdx.x * 256 + threadIdx.x] = 0.f;
}

// ---------------------------------------------------------------------------
// Kernel T: f16 copies of pw1_w ([o][c], K-contiguous) and pw_w[:, :384].
// ---------------------------------------------------------------------------
__global__ __launch_bounds__(256) void kT(const float* __restrict__ pw1_w,
                                          const float* __restrict__ pw_w,
                                          float* __restrict__ ws) {
  f16* wt1f = (f16*)(ws + WS_WT1F);
  f16* wt2f = (f16*)(ws + WS_WT2F);
  int t = blockIdx.x * 256 + threadIdx.x;
  if (t < C * M) wt1f[t] = (f16)pw1_w[t];
  if (t < 384 * O) {
    int o = t / 384, cc = t % 384;
    wt2f[t] = (f16)pw_w[(size_t)o * 768 + cc];
  }
}

// ---------------------------------------------------------------------------
// Kernel B: per-batch block; exact fp32 scoring path (unchanged from R2).
// ---------------------------------------------------------------------------
__global__ __launch_bounds__(256) void kB(const float* __restrict__ pw1_w,
                                          const float* __restrict__ pw1_b,
                                          const float* __restrict__ fc1_w,
                                          const float* __restrict__ fc1_b,
                                          const float* __restrict__ fc2_w,
                                          const float* __restrict__ fc2_b,
                                          float* __restrict__ ws) {
  int b = blockIdx.x;
  const float* meanx = ws + WS_MEANX + b * C;
  float* maskg = ws + WS_MASK;
  __shared__ float s_gap[M];
  __shared__ float s_hid[512];
  __shared__ float s_sc[M];
  int t = threadIdx.x;
  int lane = t & 63, wv = t >> 6;

  float4 mx = ((const float4*)meanx)[lane];
  for (int o0 = wv * 64; o0 < wv * 64 + 64; o0 += 4) {
    float s[4];
#pragma unroll
    for (int j = 0; j < 4; j++) {
      float4 w = ((const float4*)(pw1_w + (size_t)(o0 + j) * C))[lane];
      s[j] = mx.x * w.x + mx.y * w.y + mx.z * w.z + mx.w * w.w;
    }
#pragma unroll
    for (int off = 32; off > 0; off >>= 1)
#pragma unroll
      for (int j = 0; j < 4; j++) s[j] += __shfl_xor(s[j], off, 64);
    if (lane == 0) {
#pragma unroll
      for (int j = 0; j < 4; j++) s_gap[o0 + j] = s[j] + pw1_b[o0 + j];
    }
  }
  __syncthreads();

  float4 g4 = ((const float4*)s_gap)[lane];
  for (int j0 = wv * 128; j0 < wv * 128 + 128; j0 += 4) {
    float s[4];
#pragma unroll
    for (int j = 0; j < 4; j++) {
      float4 w = ((const float4*)(fc1_w + (size_t)(j0 + j) * M))[lane];
      s[j] = g4.x * w.x + g4.y * w.y + g4.z * w.z + g4.w * w.w;
    }
#pragma unroll
    for (int off = 32; off > 0; off >>= 1)
#pragma unroll
      for (int j = 0; j < 4; j++) s[j] += __shfl_xor(s[j], off, 64);
    if (lane == 0) {
#pragma unroll
      for (int j = 0; j < 4; j++) {
        float v = s[j] + fc1_b[j0 + j];
        s_hid[j0 + j] = v > 0.f ? v : 0.f;
      }
    }
  }
  __syncthreads();

  float4 h0 = ((const float4*)s_hid)[lane];
  float4 h1 = ((const float4*)s_hid)[lane + 64];
  for (int o0 = wv * 64; o0 < wv * 64 + 64; o0 += 4) {
    float s[4];
#pragma unroll
    for (int j = 0; j < 4; j++) {
      const float4* wr = (const float4*)(fc2_w + (size_t)(o0 + j) * 512);
      float4 w0 = wr[lane];
      float4 w1 = wr[lane + 64];
      s[j] = h0.x * w0.x + h0.y * w0.y + h0.z * w0.z + h0.w * w0.w +
             h1.x * w1.x + h1.y * w1.y + h1.z * w1.z + h1.w * w1.w;
    }
#pragma unroll
    for (int off = 32; off > 0; off >>= 1)
#pragma unroll
      for (int j = 0; j < 4; j++) s[j] += __shfl_xor(s[j], off, 64);
    if (lane == 0) {
#pragma unroll
      for (int j = 0; j < 4; j++) {
        float v = s[j] + fc2_b[o0 + j];
        s_sc[o0 + j] = 1.f / (1.f + expf(-v));
      }
    }
  }
  __syncthreads();

  {
    int j = t;
    float sj = s_sc[j];
    int cnt = 0;
    for (int m = 0; m < M; m++) {
      float sm = s_sc[m];
      cnt += (sm > sj) || (sm == sj && m < j);
    }
    maskg[b * M + j] = (cnt < K) ? 1.f : 0.f;
  }
}

// ---------------------------------------------------------------------------
// Kernel Cm: h = relu(pw1(x)) via f16 MFMA. Block = 256 o x 64 p, K=256.
// LDS in fragment-linear order (conflict-free b128). Epilogue: sel f16
// (unmasked; mask folded into conv weights) + gap2sum via shuffle reduce.
// ---------------------------------------------------------------------------
__global__ __launch_bounds__(256) void kCm(const float* __restrict__ x,
                                           const float* __restrict__ pw1_b,
                                           float* __restrict__ ws) {
  const f16* wt1f = (const f16*)(ws + WS_WT1F);
  float* gap2sum  = ws + WS_G2;
  f16* selh       = (f16*)(ws + WS_SELH);
  int b  = blockIdx.z;
  int p0 = blockIdx.x * 64;
  __shared__ f16 Af[256 * 32];  // 1024 chunks of 16B, fragment-linear
  __shared__ f16 Bf[64 * 32];   // 256 chunks

  int t = threadIdx.x, l = t & 63, w = t >> 6;
  int q = l >> 4, n = l & 15;
  const float* xb = x + (size_t)b * C * HW;

  f32x4 acc[4][4];
#pragma unroll
  for (int i = 0; i < 4; i++)
#pragma unroll
    for (int j = 0; j < 4; j++)
#pragma unroll
      for (int r = 0; r < 4; r++) acc[i][j][r] = 0.f;

  for (int k0 = 0; k0 < C; k0 += 32) {
    // Stage A: Wt1f rows (o-major, c-contiguous), 1024 chunks
#pragma unroll
    for (int i = 0; i < 4; i++) {
      int ch = t + i * 256;
      int mt = ch >> 6, qq = (ch >> 4) & 3, m = ch & 15;
      f16x8 v = *(const f16x8*)&wt1f[(size_t)(mt * 16 + m) * C + k0 + qq * 8];
      ((f16x8*)Af)[ch] = v;
    }
    // Stage B: x f32 -> f16, k-strided gather (coalesced across lanes)
    {
      int ch = t;
      int nt = ch >> 6, qq = (ch >> 4) & 3, nn = ch & 15;
      int p = p0 + nt * 16 + nn;
      f16x8 fr;
#pragma unroll
      for (int j = 0; j < 8; j++)
        fr[j] = (f16)xb[(size_t)(k0 + qq * 8 + j) * HW + p];
      ((f16x8*)Bf)[ch] = fr;
    }
    __syncthreads();
    f16x8 bfr[4], afr[4];
#pragma unroll
    for (int nt = 0; nt < 4; nt++) bfr[nt] = ((const f16x8*)Bf)[nt * 64 + l];
#pragma unroll
    for (int mt = 0; mt < 4; mt++) afr[mt] = ((const f16x8*)Af)[(w * 4 + mt) * 64 + l];
#pragma unroll
    for (int mt = 0; mt < 4; mt++)
#pragma unroll
      for (int nt = 0; nt < 4; nt++)
        acc[mt][nt] = __builtin_amdgcn_mfma_f32_16x16x32_f16(afr[mt], bfr[nt],
                                                             acc[mt][nt], 0, 0, 0);
    __syncthreads();
  }

  // Epilogue: bias + relu; sel f16 store (o<128); gap2sum partial sums
#pragma unroll
  for (int mt = 0; mt < 4; mt++) {
    float rsum[4] = {0.f, 0.f, 0.f, 0.f};
    int obase = w * 64 + mt * 16 + q * 4;
    float bias[4];
#pragma unroll
    for (int r = 0; r < 4; r++) bias[r] = pw1_b[obase + r];
#pragma unroll
    for (int nt = 0; nt < 4; nt++) {
      int p = p0 + nt * 16 + n;
#pragma unroll
      for (int r = 0; r < 4; r++) {
        float h = acc[mt][nt][r] + bias[r];
        h = h > 0.f ? h : 0.f;
        rsum[r] += h;
        int o = obase + r;
        if (o < K) selh[((size_t)(b * K + o)) * HW + p] = (f16)h;
      }
    }
#pragma unroll
    for (int off = 1; off < 16; off <<= 1)
#pragma unroll
      for (int r = 0; r < 4; r++) rsum[r] += __shfl_xor(rsum[r], off, 64);
    if (n == 0) {
#pragma unroll
      for (int r = 0; r < 4; r++)
        atomicAdd(&gap2sum[b * M + obase + r], rsum[r]);
    }
  }
}

// ---------------------------------------------------------------------------
// Kernel D1 (1 block): offsets from gap2; emit per-(b,branch) scale/shift.
// ---------------------------------------------------------------------------
__global__ __launch_bounds__(256) void kD1(const float* __restrict__ off_w,
                                           const float* __restrict__ off_b,
                                           float* __restrict__ ws) {
  const float* gap2sum = ws + WS_G2;
  float* offv = ws + WS_OFF;  // [0..23]=scale(b*3+i), [24..47]=shift
  __shared__ float s_off[48];
  int t = threadIdx.x;
  int lane = t & 63, wv = t >> 6;
  for (int id = wv; id < 48; id += 4) {
    int b = id / 6, j = id % 6;
    float4 g = ((const float4*)(gap2sum + b * M))[lane];
    float4 w = ((const float4*)(off_w + (size_t)j * M))[lane];
    float s = (g.x * w.x + g.y * w.y + g.z * w.z + g.w * w.w) * (1.f / HW);
#pragma unroll
    for (int off = 32; off > 0; off >>= 1) s += __shfl_xor(s, off, 64);
    if (lane == 0) s_off[id] = tanhf(s + off_b[j]);
  }
  __syncthreads();
  if (t < 24) {
    int b = t / 3, i = t % 3;
    offv[t]      = 1.f + 1.f / (1.f + expf(-s_off[b * 6 + 2 * i]));
    offv[24 + t] = tanhf(s_off[b * 6 + 2 * i + 1]);
  }
}

// ---------------------------------------------------------------------------
// Kernel D2: effective depthwise weights, with top-k mask folded in.
// ---------------------------------------------------------------------------
__global__ __launch_bounds__(256) void kD2(const float* __restrict__ dw3,
                                           const float* __restrict__ dw5,
                                           const float* __restrict__ dw7,
                                           float* __restrict__ ws) {
  const float* offv  = ws + WS_OFF;
  const float* maskg = ws + WS_MASK;
  float* wE3 = ws + WS_WE3;
  float* wE5 = ws + WS_WE5;
  float* wE7 = ws + WS_WE7;
  int tid = blockIdx.x * 256 + threadIdx.x;
  int stride = gridDim.x * 256;
  for (int i = tid; i < B * K * 9; i += stride) {
    int b = i / (K * 9), rem = i % (K * 9), c = rem / 9;
    wE3[i] = (dw3[rem] * offv[b * 3 + 0] + offv[24 + b * 3 + 0]) * maskg[b * M + c];
  }
  for (int i = tid; i < B * K * 25; i += stride) {
    int b = i / (K * 25), rem = i % (K * 25), c = rem / 25;
    wE5[i] = (dw5[rem] * offv[b * 3 + 1] + offv[24 + b * 3 + 1]) * maskg[b * M + c];
  }
  for (int i = tid; i < B * K * 49; i += stride) {
    int b = i / (K * 49), rem = i % (K * 49), c = rem / 49;
    wE7[i] = (dw7[rem] * offv[b * 3 + 2] + offv[24 + b * 3 + 2]) * maskg[b * M + c];
  }
}

// ---------------------------------------------------------------------------
// Kernel Em: merged depthwise conv — one halo fill (P=3 superset), all three
// kernel sizes computed per plane chunk; f16 in, f16 out x3 branches.
// ---------------------------------------------------------------------------
__global__ __launch_bounds__(256) void kEm(const float* __restrict__ ws_ro,
                                           float* __restrict__ ws) {
  constexpr int SH = 38, SW = 134;  // 32+2*3, 128+2*3
  __shared__ float sm[SH][SW];
  const f16* selh = (const f16*)(ws_ro + WS_SELH);
  f16* yh         = (f16*)(ws + WS_YH);
  int blk = blockIdx.x;
  int chunk = blk & 3;
  int plane = blk >> 2;  // b*K + c
  int b = plane >> 7, c = plane & 127;
  int r0 = chunk * 32;
  const f16* in = selh + (size_t)plane * HW;
  for (int i = threadIdx.x; i < SH * SW; i += 256) {
    int rr = i / SW, cc = i % SW;
    int gy = r0 - 3 + rr, gx = cc - 3;
    float v = 0.f;
    if (gy >= 0 && gy < H && gx >= 0 && gx < W) v = (float)in[gy * W + gx];
    sm[rr][cc] = v;
  }
  __syncthreads();
  int col   = threadIdx.x & 127;
  int rhalf = threadIdx.x >> 7;

  const float* wE[3] = {ws_ro + WS_WE3 + (size_t)plane * 9,
                        ws_ro + WS_WE5 + (size_t)plane * 25,
                        ws_ro + WS_WE7 + (size_t)plane * 49};

#define CONV_BRANCH(KS, BR)                                                    \
  {                                                                            \
    constexpr int P = (KS - 1) / 2;                                            \
    float w[KS * KS];                                                          \
    _Pragma("unroll") for (int i = 0; i < KS * KS; i++) w[i] = wE[BR][i];      \
    float acc[16];                                                             \
    _Pragma("unroll") for (int r = 0; r < 16; r++) acc[r] = 0.f;               \
    _Pragma("unroll") for (int iy = 0; iy < 16 + 2 * P; iy++) {                \
      float v[KS];                                                             \
      _Pragma("unroll") for (int dx = 0; dx < KS; dx++)                        \
          v[dx] = sm[rhalf * 16 + iy + (3 - P)][col + (3 - P) + dx];           \
      _Pragma("unroll") for (int rr = 0; rr < 16; rr++) {                      \
        int dy = iy - rr;                                                      \
        if (dy >= 0 && dy < KS) {                                              \
          _Pragma("unroll") for (int dx = 0; dx < KS; dx++)                    \
              acc[rr] += v[dx] * w[dy * KS + dx];                              \
        }                                                                      \
      }                                                                        \
    }                                                                          \
    f16* outp = yh + ((size_t)(BR * B + b) * K + c) * HW;                      \
    _Pragma("unroll") for (int rr = 0; rr < 16; rr++)                          \
        outp[(size_t)(r0 + rhalf * 16 + rr) * W + col] = (f16)acc[rr];         \
  }

  CONV_BRANCH(3, 0)
  CONV_BRANCH(5, 1)
  CONV_BRANCH(7, 2)
#undef CONV_BRANCH
}

// ---------------------------------------------------------------------------
// Kernel Fm: merged final pointwise, f16 MFMA, K=384 (all 3 branches).
// Block = 256 o x 64 p. Epilogue: + pw_b + residual x, single out pass.
// ---------------------------------------------------------------------------
__global__ __launch_bounds__(256) void kFm(const float* __restrict__ x,
                                           const float* __restrict__ pw_b,
                                           const float* __restrict__ ws,
                                           float* __restrict__ out) {
  const f16* wt2f = (const f16*)(ws + WS_WT2F);
  const f16* yh   = (const f16*)(ws + WS_YH);
  int b  = blockIdx.z;
  int p0 = blockIdx.x * 64;
  __shared__ f16 Af[256 * 32];
  __shared__ f16 Bf[64 * 32];

  int t = threadIdx.x, l = t & 63, w = t >> 6;
  int q = l >> 4, n = l & 15;

  f32x4 acc[4][4];
#pragma unroll
  for (int i = 0; i < 4; i++)
#pragma unroll
    for (int j = 0; j < 4; j++)
#pragma unroll
      for (int r = 0; r < 4; r++) acc[i][j][r] = 0.f;

  for (int k0 = 0; k0 < 384; k0 += 32) {
    int br = k0 >> 7, kk = k0 & 127;
    const f16* ybr = yh + (size_t)(br * B + b) * K * HW;
#pragma unroll
    for (int i = 0; i < 4; i++) {
      int ch = t + i * 256;
      int mt = ch >> 6, qq = (ch >> 4) & 3, m = ch & 15;
      f16x8 v = *(const f16x8*)&wt2f[(size_t)(mt * 16 + m) * 384 + k0 + qq * 8];
      ((f16x8*)Af)[ch] = v;
    }
    {
      int ch = t;
      int nt = ch >> 6, qq = (ch >> 4) & 3, nn = ch & 15;
      int p = p0 + nt * 16 + nn;
      f16x8 fr;
#pragma unroll
      for (int j = 0; j < 8; j++)
        fr[j] = ybr[(size_t)(kk + qq * 8 + j) * HW + p];
      ((f16x8*)Bf)[ch] = fr;
    }
    __syncthreads();
    f16x8 bfr[4], afr[4];
#pragma unroll
    for (int nt = 0; nt < 4; nt++) bfr[nt] = ((const f16x8*)Bf)[nt * 64 + l];
#pragma unroll
    for (int mt = 0; mt < 4; mt++) afr[mt] = ((const f16x8*)Af)[(w * 4 + mt) * 64 + l];
#pragma unroll
    for (int mt = 0; mt < 4; mt++)
#pragma unroll
      for (int nt = 0; nt < 4; nt++)
        acc[mt][nt] = __builtin_amdgcn_mfma_f32_16x16x32_f16(afr[mt], bfr[nt],
                                                             acc[mt][nt], 0, 0, 0);
    __syncthreads();
  }

#pragma unroll
  for (int mt = 0; mt < 4; mt++) {
    int obase = w * 64 + mt * 16 + q * 4;
    float bias[4];
#pragma unroll
    for (int r = 0; r < 4; r++) bias[r] = pw_b[obase + r];
#pragma unroll
    for (int nt = 0; nt < 4; nt++) {
      int p = p0 + nt * 16 + n;
#pragma unroll
      for (int r = 0; r < 4; r++) {
        size_t idx = ((size_t)b * O + obase + r) * HW + p;
        out[idx] = acc[mt][nt][r] + bias[r] + x[idx];
      }
    }
  }
}

// ---------------------------------------------------------------------------
extern "C" void kernel_launch(void* const* d_in, const int* in_sizes, int n_in,
                              void* d_out, int out_size, void* d_ws, size_t ws_size,
                              hipStream_t stream) {
  const float* x     = (const float*)d_in[0];
  const float* pw1_w = (const float*)d_in[1];
  const float* pw1_b = (const float*)d_in[2];
  const float* fc1_w = (const float*)d_in[3];
  const float* fc1_b = (const float*)d_in[4];
  const float* fc2_w = (const float*)d_in[5];
  const float* fc2_b = (const float*)d_in[6];
  const float* off_w = (const float*)d_in[7];
  const float* off_b = (const float*)d_in[8];
  const float* dw3   = (const float*)d_in[9];
  const float* dw5   = (const float*)d_in[10];
  const float* dw7   = (const float*)d_in[11];
  const float* pw_w  = (const float*)d_in[12];
  const float* pw_b  = (const float*)d_in[13];
  float* out = (float*)d_out;
  float* ws  = (float*)d_ws;

  kA<<<B * C, 256, 0, stream>>>(x, ws);
  kT<<<384, 256, 0, stream>>>(pw1_w, pw_w, ws);
  kB<<<B, 256, 0, stream>>>(pw1_w, pw1_b, fc1_w, fc1_b, fc2_w, fc2_b, ws);
  kCm<<<dim3(HW / 64, 1, B), 256, 0, stream>>>(x, pw1_b, ws);
  kD1<<<1, 256, 0, stream>>>(off_w, off_b, ws);
  kD2<<<84, 256, 0, stream>>>(dw3, dw5, dw7, ws);
  kEm<<<B * K * 4, 256, 0, stream>>>(ws, ws);
  kFm<<<dim3(HW / 64, 1, B), 256, 0, stream>>>(x, pw_b, ws, out);
}